// Round 1
// baseline (482.146 us; speedup 1.0000x reference)
//
#include <hip/hip_runtime.h>
#include <math.h>

#define N_TOK 65536
#define DIM   512
#define HID   102
#define HPAD  128   // fc1 padded hidden (cols 102..127 zero)
#define HROW  105   // hs LDS row pitch (9*ti mod 32 -> conflict-free)
#define KTOK  64
#define LN_EPS 1e-5f

// ws layout (float offsets)
#define WS_LOGITS 0
#define WS_W1P (KTOK * N_TOK)            // 4194304
#define WS_B1P (WS_W1P + DIM * HPAD)     // + 65536
#define WS_W2P (WS_B1P + HPAD)           // + 128
#define WS_SMAX (WS_W2P + 104 * KTOK)    // + 6656
#define WS_SINV (WS_SMAX + KTOK)

// ---------------- prep: zero out, build padded weights ----------------
__global__ __launch_bounds__(256) void prep_k(const float* __restrict__ W1,
                                              const float* __restrict__ b1,
                                              const float* __restrict__ W2,
                                              float* __restrict__ W1p,
                                              float* __restrict__ b1p,
                                              float* __restrict__ W2p,
                                              float* __restrict__ out) {
    int idx = blockIdx.x * 256 + threadIdx.x;   // grid 256x256 = 65536
    // W1p [512][128]
    {
        int d = idx >> 7, j = idx & 127;
        W1p[idx] = (j < HID) ? W1[d * HID + j] : 0.0f;
    }
    if (idx < KTOK * DIM) out[idx] = 0.0f;          // zero d_out (32768)
    if (idx < HPAD) b1p[idx] = (idx < HID) ? b1[idx] : 0.0f;
    if (idx < 104 * KTOK) {                          // W2p [104][64]
        int j = idx >> 6, k = idx & 63;
        W2p[idx] = (j < HID) ? W2[j * KTOK + k] : 0.0f;
    }
}

// ---------------- scorer: LN + fc1 + GELU + fc2 -> logits[k][n] ----------------
__global__ __launch_bounds__(256, 2) void scorer_k(const float* __restrict__ x,
                                                   const float* __restrict__ gamma,
                                                   const float* __restrict__ beta,
                                                   const float* __restrict__ W1p,
                                                   const float* __restrict__ b1p,
                                                   const float* __restrict__ W2p,
                                                   const float* __restrict__ b2,
                                                   const float* __restrict__ scale,
                                                   float* __restrict__ logits) {
    __shared__ float xs[32][DIM];     // 64 KB, normalized tokens
    __shared__ float hs[32][HROW];    // 13.4 KB, gelu outputs
    const int tid = threadIdx.x;
    const int lane = tid & 63;
    const int w = tid >> 6;           // wave id 0..3
    const int n0 = blockIdx.x * 32;

    // ---- LayerNorm: wave w handles rows 8w..8w+7 ----
    {
        const float4 g0 = *(const float4*)&gamma[lane * 4];
        const float4 g1 = *(const float4*)&gamma[256 + lane * 4];
        const float4 be0 = *(const float4*)&beta[lane * 4];
        const float4 be1 = *(const float4*)&beta[256 + lane * 4];
        for (int r = 0; r < 8; ++r) {
            const int row = w * 8 + r;
            const float* xr = x + (size_t)(n0 + row) * DIM;
            float4 a = *(const float4*)&xr[lane * 4];
            float4 b = *(const float4*)&xr[256 + lane * 4];
            float s = a.x + a.y + a.z + a.w + b.x + b.y + b.z + b.w;
            float ss = a.x * a.x + a.y * a.y + a.z * a.z + a.w * a.w +
                       b.x * b.x + b.y * b.y + b.z * b.z + b.w * b.w;
            #pragma unroll
            for (int o = 32; o >= 1; o >>= 1) {
                s += __shfl_xor(s, o);
                ss += __shfl_xor(ss, o);
            }
            const float mu = s * (1.0f / 512.0f);
            const float var = ss * (1.0f / 512.0f) - mu * mu;
            const float inv = rsqrtf(var + LN_EPS);
            float4 o0, o1;
            o0.x = (a.x - mu) * inv * g0.x + be0.x;
            o0.y = (a.y - mu) * inv * g0.y + be0.y;
            o0.z = (a.z - mu) * inv * g0.z + be0.z;
            o0.w = (a.w - mu) * inv * g0.w + be0.w;
            o1.x = (b.x - mu) * inv * g1.x + be1.x;
            o1.y = (b.y - mu) * inv * g1.y + be1.y;
            o1.z = (b.z - mu) * inv * g1.z + be1.z;
            o1.w = (b.w - mu) * inv * g1.w + be1.w;
            *(float4*)&xs[row][lane * 4] = o0;
            *(float4*)&xs[row][256 + lane * 4] = o1;
        }
    }
    __syncthreads();

    // ---- fc1 + GELU: 4 tokens x 4 hidden per thread ----
    {
        const int tig = tid >> 5;      // 0..7 -> rows tig*4..+3
        const int jt = tid & 31;       // j quad: jt*4..+3 (HPAD=128)
        const float* wcol = W1p + jt * 4;
        const float* r0 = xs[tig * 4 + 0];
        const float* r1 = xs[tig * 4 + 1];
        const float* r2 = xs[tig * 4 + 2];
        const float* r3 = xs[tig * 4 + 3];
        float acc[4][4] = {};
        #pragma unroll 4
        for (int d = 0; d < DIM; ++d) {
            const float4 w4 = *(const float4*)&wcol[d * HPAD];
            const float v0 = r0[d], v1 = r1[d], v2 = r2[d], v3 = r3[d];
            acc[0][0] = fmaf(v0, w4.x, acc[0][0]);
            acc[0][1] = fmaf(v0, w4.y, acc[0][1]);
            acc[0][2] = fmaf(v0, w4.z, acc[0][2]);
            acc[0][3] = fmaf(v0, w4.w, acc[0][3]);
            acc[1][0] = fmaf(v1, w4.x, acc[1][0]);
            acc[1][1] = fmaf(v1, w4.y, acc[1][1]);
            acc[1][2] = fmaf(v1, w4.z, acc[1][2]);
            acc[1][3] = fmaf(v1, w4.w, acc[1][3]);
            acc[2][0] = fmaf(v2, w4.x, acc[2][0]);
            acc[2][1] = fmaf(v2, w4.y, acc[2][1]);
            acc[2][2] = fmaf(v2, w4.z, acc[2][2]);
            acc[2][3] = fmaf(v2, w4.w, acc[2][3]);
            acc[3][0] = fmaf(v3, w4.x, acc[3][0]);
            acc[3][1] = fmaf(v3, w4.y, acc[3][1]);
            acc[3][2] = fmaf(v3, w4.z, acc[3][2]);
            acc[3][3] = fmaf(v3, w4.w, acc[3][3]);
        }
        const float4 bb = *(const float4*)&b1p[jt * 4];
        const float bv[4] = {bb.x, bb.y, bb.z, bb.w};
        #pragma unroll
        for (int i = 0; i < 4; ++i) {
            #pragma unroll
            for (int c = 0; c < 4; ++c) {
                const int j = jt * 4 + c;
                const float t = acc[i][c] + bv[c];
                const float g = 0.5f * t * (1.0f + erff(t * 0.70710678118f));
                if (j < HID) hs[tig * 4 + i][j] = g;
            }
        }
    }
    __syncthreads();

    // ---- fc2 + scale: 8 k per thread ----
    {
        const int kg = tid >> 5;       // 0..7 -> k = kg*8..+8
        const int ti = tid & 31;       // token in tile
        float acc[8] = {};
        for (int j = 0; j < HID; ++j) {
            const float v = hs[ti][j];
            const float4 wa = *(const float4*)&W2p[j * KTOK + kg * 8];
            const float4 wb = *(const float4*)&W2p[j * KTOK + kg * 8 + 4];
            acc[0] = fmaf(v, wa.x, acc[0]);
            acc[1] = fmaf(v, wa.y, acc[1]);
            acc[2] = fmaf(v, wa.z, acc[2]);
            acc[3] = fmaf(v, wa.w, acc[3]);
            acc[4] = fmaf(v, wb.x, acc[4]);
            acc[5] = fmaf(v, wb.y, acc[5]);
            acc[6] = fmaf(v, wb.z, acc[6]);
            acc[7] = fmaf(v, wb.w, acc[7]);
        }
        const float sc = scale[0];
        #pragma unroll
        for (int i = 0; i < 8; ++i) {
            const int k = kg * 8 + i;
            logits[(size_t)k * N_TOK + n0 + ti] = (acc[i] + b2[k]) * sc;
        }
    }
}

// ---------------- stats: per-k max and 1/sum(exp) ----------------
__global__ __launch_bounds__(256, 4) void stats_k(const float* __restrict__ logits,
                                                  float* __restrict__ smax,
                                                  float* __restrict__ sinv) {
    const int k = blockIdx.x;
    const int tid = threadIdx.x;
    const float* row = logits + (size_t)k * N_TOK;
    __shared__ float red[4];

    float m = -1e30f;
    for (int i = tid * 4; i < N_TOK; i += 1024) {
        const float4 v = *(const float4*)&row[i];
        m = fmaxf(fmaxf(m, fmaxf(v.x, v.y)), fmaxf(v.z, v.w));
    }
    #pragma unroll
    for (int o = 32; o >= 1; o >>= 1) m = fmaxf(m, __shfl_xor(m, o));
    if ((tid & 63) == 0) red[tid >> 6] = m;
    __syncthreads();
    m = fmaxf(fmaxf(red[0], red[1]), fmaxf(red[2], red[3]));
    __syncthreads();

    float s = 0.0f;
    for (int i = tid * 4; i < N_TOK; i += 1024) {
        const float4 v = *(const float4*)&row[i];
        s += expf(v.x - m) + expf(v.y - m) + expf(v.z - m) + expf(v.w - m);
    }
    #pragma unroll
    for (int o = 32; o >= 1; o >>= 1) s += __shfl_xor(s, o);
    if ((tid & 63) == 0) red[tid >> 6] = s;
    __syncthreads();
    if (tid == 0) {
        smax[k] = m;
        sinv[k] = 1.0f / (red[0] + red[1] + red[2] + red[3]);
    }
}

// ---------------- agg: out[k][d] += sum_n p[k][n] * x[n][d] ----------------
__global__ __launch_bounds__(256, 2) void agg_k(const float* __restrict__ x,
                                                const float* __restrict__ logits,
                                                const float* __restrict__ smax,
                                                const float* __restrict__ sinv,
                                                float* __restrict__ out) {
    __shared__ float ps[64][64];      // 16 KB probs chunk
    const int tid = threadIdx.x;
    const int dg = blockIdx.y;        // 0..3 (128 cols each)
    const int tb = blockIdx.x;        // 0..127 (512 tokens each)
    const int kt = tid >> 5;          // 0..7 -> k = kt*8..+8
    const int dt = tid & 31;
    const int dbase = dg * 128 + dt * 4;
    const int n_start = tb * 512;
    float acc[8][4] = {};

    for (int c = 0; c < 8; ++c) {
        const int n0 = n_start + c * 64;
        // stage softmax probs for this 64-token chunk
        {
            const int kl = tid >> 4;           // 0..15
            const int np = (tid & 15) * 4;     // 0..60
            #pragma unroll
            for (int rep = 0; rep < 4; ++rep) {
                const int k = kl + rep * 16;
                const float4 v = *(const float4*)&logits[(size_t)k * N_TOK + n0 + np];
                const float mk = smax[k];
                const float ik = sinv[k];
                ps[k][np + 0] = expf(v.x - mk) * ik;
                ps[k][np + 1] = expf(v.y - mk) * ik;
                ps[k][np + 2] = expf(v.z - mk) * ik;
                ps[k][np + 3] = expf(v.w - mk) * ik;
            }
        }
        __syncthreads();
        #pragma unroll 4
        for (int n = 0; n < 64; ++n) {
            const float4 xv = *(const float4*)&x[(size_t)(n0 + n) * DIM + dbase];
            #pragma unroll
            for (int i = 0; i < 8; ++i) {
                const float p = ps[kt * 8 + i][n];
                acc[i][0] = fmaf(p, xv.x, acc[i][0]);
                acc[i][1] = fmaf(p, xv.y, acc[i][1]);
                acc[i][2] = fmaf(p, xv.z, acc[i][2]);
                acc[i][3] = fmaf(p, xv.w, acc[i][3]);
            }
        }
        __syncthreads();
    }
    #pragma unroll
    for (int i = 0; i < 8; ++i) {
        const int k = kt * 8 + i;
        atomicAdd(&out[k * DIM + dbase + 0], acc[i][0]);
        atomicAdd(&out[k * DIM + dbase + 1], acc[i][1]);
        atomicAdd(&out[k * DIM + dbase + 2], acc[i][2]);
        atomicAdd(&out[k * DIM + dbase + 3], acc[i][3]);
    }
}

extern "C" void kernel_launch(void* const* d_in, const int* in_sizes, int n_in,
                              void* d_out, int out_size, void* d_ws, size_t ws_size,
                              hipStream_t stream) {
    const float* x     = (const float*)d_in[0];
    const float* gamma = (const float*)d_in[1];
    const float* beta  = (const float*)d_in[2];
    const float* W1    = (const float*)d_in[3];
    const float* b1    = (const float*)d_in[4];
    const float* W2    = (const float*)d_in[5];
    const float* b2    = (const float*)d_in[6];
    const float* scale = (const float*)d_in[7];
    float* out = (float*)d_out;
    float* ws  = (float*)d_ws;

    float* logits = ws + WS_LOGITS;
    float* W1p    = ws + WS_W1P;
    float* b1p    = ws + WS_B1P;
    float* W2p    = ws + WS_W2P;
    float* smax   = ws + WS_SMAX;
    float* sinv   = ws + WS_SINV;

    hipLaunchKernelGGL(prep_k, dim3(256), dim3(256), 0, stream,
                       W1, b1, W2, W1p, b1p, W2p, out);
    hipLaunchKernelGGL(scorer_k, dim3(N_TOK / 32), dim3(256), 0, stream,
                       x, gamma, beta, W1p, b1p, W2p, b2, scale, logits);
    hipLaunchKernelGGL(stats_k, dim3(KTOK), dim3(256), 0, stream,
                       logits, smax, sinv);
    hipLaunchKernelGGL(agg_k, dim3(128, 4), dim3(256), 0, stream,
                       x, logits, smax, sinv, out);
}

// Round 2
// 269.812 us; speedup vs baseline: 1.7870x; 1.7870x over previous
//
#include <hip/hip_runtime.h>
#include <math.h>

#define N_TOK 65536
#define DIM   512
#define HID   102
#define HPAD  128
#define KTOK  64
#define LN_EPS 1e-5f

typedef __attribute__((ext_vector_type(8))) short short8;
typedef __attribute__((ext_vector_type(4))) float f32x4;

// ws layout (float offsets)
#define WS_LOGITS 0u
#define WS_PART   4194304u                 // 128*64*512 = 4194304 floats
#define WS_W1H    (WS_PART + 4194304u)     // 65536 ushort = 32768 floats
#define WS_W1L    (WS_W1H + 32768u)
#define WS_W2T    (WS_W1L + 32768u)        // 8192 ushort = 4096 floats
#define WS_B1P    (WS_W2T + 4096u)
#define WS_SMAX   (WS_B1P + 128u)
#define WS_SINV   (WS_SMAX + 64u)

__device__ __forceinline__ unsigned short f2bf(float f) {
    unsigned int u = __float_as_uint(f);
    unsigned int r = (u + 0x7fffu + ((u >> 16) & 1u)) >> 16;
    return (unsigned short)r;
}
__device__ __forceinline__ float bf2f(unsigned short h) {
    return __uint_as_float(((unsigned int)h) << 16);
}

// ---------------- prep: bf16 split weights, transposed ----------------
__global__ __launch_bounds__(256) void prep_k(const float* __restrict__ W1,
                                              const float* __restrict__ b1,
                                              const float* __restrict__ W2,
                                              unsigned short* __restrict__ W1h,
                                              unsigned short* __restrict__ W1l,
                                              unsigned short* __restrict__ W2t,
                                              float* __restrict__ b1p) {
    const int idx = blockIdx.x * 256 + threadIdx.x;   // 0..65535
    {   // W1t [128 j][512 d] = W1[d][j], split hi+lo
        const int j = idx >> 9, d = idx & 511;
        const float w = (j < HID) ? W1[d * HID + j] : 0.0f;
        const unsigned short h = f2bf(w);
        W1h[idx] = h;
        W1l[idx] = f2bf(w - bf2f(h));
    }
    if (idx < KTOK * HPAD) {  // W2t [64 k][128 j] = W2[j][k]
        const int k = idx >> 7, j = idx & 127;
        W2t[idx] = (j < HID) ? f2bf(W2[j * KTOK + k]) : (unsigned short)0;
    }
    if (idx < HPAD) b1p[idx] = (idx < HID) ? b1[idx] : 0.0f;
}

// ---------------- scorer: LN + fc1(MFMA, W-split) + GELU + fc2(MFMA) ----------------
__global__ __launch_bounds__(256, 2) void scorer_k(const float* __restrict__ x,
                                                   const float* __restrict__ gamma,
                                                   const float* __restrict__ beta,
                                                   const unsigned short* __restrict__ W1h,
                                                   const unsigned short* __restrict__ W1l,
                                                   const unsigned short* __restrict__ W2t,
                                                   const float* __restrict__ b1p,
                                                   const float* __restrict__ b2,
                                                   const float* __restrict__ scale,
                                                   float* __restrict__ logits) {
    __shared__ char smem[64 * 1024 + 16 * 1024];
    char* xs = smem;                         // [64 rows][1024 B] bf16, XOR-swizzled
    char* hsm = smem + 64 * 1024;            // [64 rows][256 B] bf16, XOR-swizzled
    float* lt = (float*)smem;                // [64 k][64 tok] fp32, aliases xs (dead)

    const int tid = threadIdx.x;
    const int lane = tid & 63;
    const int w = tid >> 6;
    const int n0 = blockIdx.x * 64;
    const int l15 = lane & 15;
    const int hi = lane >> 4;

    // ---- LayerNorm -> xs bf16 (swizzled) ----
    {
        const f32x4 g0 = *(const f32x4*)&gamma[lane * 8];
        const f32x4 g1 = *(const f32x4*)&gamma[lane * 8 + 4];
        const f32x4 be0 = *(const f32x4*)&beta[lane * 8];
        const f32x4 be1 = *(const f32x4*)&beta[lane * 8 + 4];
        for (int r = 0; r < 16; ++r) {
            const int row = w * 16 + r;
            const float* xr = x + (size_t)(n0 + row) * DIM;
            const f32x4 a = *(const f32x4*)&xr[lane * 8];
            const f32x4 b = *(const f32x4*)&xr[lane * 8 + 4];
            float s = a.x + a.y + a.z + a.w + b.x + b.y + b.z + b.w;
            float ss = a.x * a.x + a.y * a.y + a.z * a.z + a.w * a.w +
                       b.x * b.x + b.y * b.y + b.z * b.z + b.w * b.w;
            #pragma unroll
            for (int o = 32; o >= 1; o >>= 1) {
                s += __shfl_xor(s, o);
                ss += __shfl_xor(ss, o);
            }
            const float mu = s * (1.0f / 512.0f);
            const float inv = rsqrtf(ss * (1.0f / 512.0f) - mu * mu + LN_EPS);
            short8 v;
            v[0] = (short)f2bf((a.x - mu) * inv * g0.x + be0.x);
            v[1] = (short)f2bf((a.y - mu) * inv * g0.y + be0.y);
            v[2] = (short)f2bf((a.z - mu) * inv * g0.z + be0.z);
            v[3] = (short)f2bf((a.w - mu) * inv * g0.w + be0.w);
            v[4] = (short)f2bf((b.x - mu) * inv * g1.x + be1.x);
            v[5] = (short)f2bf((b.y - mu) * inv * g1.y + be1.y);
            v[6] = (short)f2bf((b.z - mu) * inv * g1.z + be1.z);
            v[7] = (short)f2bf((b.w - mu) * inv * g1.w + be1.w);
            *(short8*)(xs + row * 1024 + ((lane * 16) ^ ((row & 7) << 4))) = v;
        }
    }
    __syncthreads();

    // ---- fc1: wave w computes tokens [16w,16w+16) x 128 hidden ----
    {
        const int arow = w * 16 + l15;
        const char* abase = xs + arow * 1024;
        const int asw = (arow & 7) << 4;
        f32x4 acc[8] = {};
        const unsigned short* wh0 = W1h + l15 * 512 + hi * 8;
        const unsigned short* wl0 = W1l + l15 * 512 + hi * 8;
        #pragma unroll 2
        for (int kc = 0; kc < 16; ++kc) {
            const short8 a = *(const short8*)(abase + ((kc * 64 + hi * 16) ^ asw));
            #pragma unroll
            for (int jt = 0; jt < 8; ++jt) {
                const short8 bh = *(const short8*)(wh0 + jt * 8192 + kc * 32);
                const short8 bl = *(const short8*)(wl0 + jt * 8192 + kc * 32);
                acc[jt] = __builtin_amdgcn_mfma_f32_16x16x32_bf16(a, bh, acc[jt], 0, 0, 0);
                acc[jt] = __builtin_amdgcn_mfma_f32_16x16x32_bf16(a, bl, acc[jt], 0, 0, 0);
            }
        }
        // bias + GELU -> hs bf16 (swizzled). Padded cols produce gelu(0)=0.
        #pragma unroll
        for (int jt = 0; jt < 8; ++jt) {
            const int col = jt * 16 + l15;
            const float bias = b1p[col];
            #pragma unroll
            for (int reg = 0; reg < 4; ++reg) {
                const int row = w * 16 + 4 * hi + reg;
                const float t = acc[jt][reg] + bias;
                const float g = 0.5f * t * (1.0f + erff(t * 0.70710678118f));
                *(unsigned short*)(hsm + row * 256 + ((col * 2) ^ ((row & 7) << 4))) =
                    f2bf(g);
            }
        }
    }
    __syncthreads();

    // ---- fc2: wave w computes tokens [16w,16w+16) x 64 k ----
    {
        const int arow = w * 16 + l15;
        const char* hbase = hsm + arow * 256;
        const int hsw = (arow & 7) << 4;
        f32x4 acc2[4] = {};
        #pragma unroll
        for (int kc = 0; kc < 4; ++kc) {
            const short8 a = *(const short8*)(hbase + ((kc * 64 + hi * 16) ^ hsw));
            #pragma unroll
            for (int nt = 0; nt < 4; ++nt) {
                const short8 b =
                    *(const short8*)(W2t + (nt * 16 + l15) * 128 + kc * 32 + hi * 8);
                acc2[nt] = __builtin_amdgcn_mfma_f32_16x16x32_bf16(a, b, acc2[nt], 0, 0, 0);
            }
        }
        const float sc = scale[0];
        #pragma unroll
        for (int nt = 0; nt < 4; ++nt) {
            const int k = nt * 16 + l15;
            const float bb = b2[k];
            #pragma unroll
            for (int reg = 0; reg < 4; ++reg) {
                const int token = w * 16 + 4 * hi + reg;
                *(float*)((char*)lt + k * 256 + ((token * 4) ^ ((k & 7) << 4))) =
                    (acc2[nt][reg] + bb) * sc;
            }
        }
    }
    __syncthreads();

    // ---- coalesced logits store: thread t -> row k=t>>2, tokens (t&3)*16..+16 ----
    {
        const int k = tid >> 2, q = tid & 3;
        const char* lrow = (const char*)lt + k * 256;
        const int ksw = (k & 7) << 4;
        float* dst = logits + (size_t)k * N_TOK + n0 + q * 16;
        #pragma unroll
        for (int i = 0; i < 4; ++i) {
            *(f32x4*)(dst + i * 4) =
                *(const f32x4*)(lrow + ((q * 64 + i * 16) ^ ksw));
        }
    }
}

// ---------------- stats: per-k max and 1/sum(exp) ----------------
__global__ __launch_bounds__(256, 4) void stats_k(const float* __restrict__ logits,
                                                  float* __restrict__ smax,
                                                  float* __restrict__ sinv) {
    const int k = blockIdx.x;
    const int tid = threadIdx.x;
    const float* row = logits + (size_t)k * N_TOK;
    __shared__ float red[4];

    float m = -1e30f;
    for (int i = tid * 4; i < N_TOK; i += 1024) {
        const f32x4 v = *(const f32x4*)&row[i];
        m = fmaxf(fmaxf(m, fmaxf(v.x, v.y)), fmaxf(v.z, v.w));
    }
    #pragma unroll
    for (int o = 32; o >= 1; o >>= 1) m = fmaxf(m, __shfl_xor(m, o));
    if ((tid & 63) == 0) red[tid >> 6] = m;
    __syncthreads();
    m = fmaxf(fmaxf(red[0], red[1]), fmaxf(red[2], red[3]));
    __syncthreads();

    float s = 0.0f;
    for (int i = tid * 4; i < N_TOK; i += 1024) {
        const f32x4 v = *(const f32x4*)&row[i];
        s += expf(v.x - m) + expf(v.y - m) + expf(v.z - m) + expf(v.w - m);
    }
    #pragma unroll
    for (int o = 32; o >= 1; o >>= 1) s += __shfl_xor(s, o);
    if ((tid & 63) == 0) red[tid >> 6] = s;
    __syncthreads();
    if (tid == 0) {
        smax[k] = m;
        sinv[k] = 1.0f / (red[0] + red[1] + red[2] + red[3]);
    }
}

// ---------------- agg: partial[tb][k][d] = sum over 512-token slice ----------------
__global__ __launch_bounds__(256, 2) void agg_k(const float* __restrict__ x,
                                                const float* __restrict__ logits,
                                                const float* __restrict__ smax,
                                                const float* __restrict__ sinv,
                                                float* __restrict__ part) {
    __shared__ float ps[64][64];
    const int tid = threadIdx.x;
    const int dg = blockIdx.y;
    const int tb = blockIdx.x;
    const int kt = tid >> 5;
    const int dt = tid & 31;
    const int dbase = dg * 128 + dt * 4;
    const int n_start = tb * 512;
    float acc[8][4] = {};

    for (int c = 0; c < 8; ++c) {
        const int n0 = n_start + c * 64;
        {
            const int kl = tid >> 4;
            const int np = (tid & 15) * 4;
            #pragma unroll
            for (int rep = 0; rep < 4; ++rep) {
                const int k = kl + rep * 16;
                const f32x4 v = *(const f32x4*)&logits[(size_t)k * N_TOK + n0 + np];
                const float mk = smax[k];
                const float ik = sinv[k];
                ps[k][np + 0] = expf(v.x - mk) * ik;
                ps[k][np + 1] = expf(v.y - mk) * ik;
                ps[k][np + 2] = expf(v.z - mk) * ik;
                ps[k][np + 3] = expf(v.w - mk) * ik;
            }
        }
        __syncthreads();
        #pragma unroll 4
        for (int n = 0; n < 64; ++n) {
            const f32x4 xv = *(const f32x4*)&x[(size_t)(n0 + n) * DIM + dbase];
            #pragma unroll
            for (int i = 0; i < 8; ++i) {
                const float p = ps[kt * 8 + i][n];
                acc[i][0] = fmaf(p, xv.x, acc[i][0]);
                acc[i][1] = fmaf(p, xv.y, acc[i][1]);
                acc[i][2] = fmaf(p, xv.z, acc[i][2]);
                acc[i][3] = fmaf(p, xv.w, acc[i][3]);
            }
        }
        __syncthreads();
    }
    #pragma unroll
    for (int i = 0; i < 8; ++i) {
        const int k = kt * 8 + i;
        f32x4 v;
        v.x = acc[i][0]; v.y = acc[i][1]; v.z = acc[i][2]; v.w = acc[i][3];
        *(f32x4*)&part[((size_t)tb * 64 + k) * 512 + dbase] = v;
    }
}

// ---------------- reduce: out[k][d] = sum_tb part[tb][k][d] ----------------
__global__ __launch_bounds__(256) void reduce_k(const float* __restrict__ part,
                                                float* __restrict__ out) {
    const int idx = blockIdx.x * 256 + threadIdx.x;  // 0..32767
    const int k = idx >> 9, d = idx & 511;
    float s = 0.0f;
    for (int tb = 0; tb < 128; ++tb) s += part[((size_t)tb * 64 + k) * 512 + d];
    out[idx] = s;
}

extern "C" void kernel_launch(void* const* d_in, const int* in_sizes, int n_in,
                              void* d_out, int out_size, void* d_ws, size_t ws_size,
                              hipStream_t stream) {
    const float* x     = (const float*)d_in[0];
    const float* gamma = (const float*)d_in[1];
    const float* beta  = (const float*)d_in[2];
    const float* W1    = (const float*)d_in[3];
    const float* b1    = (const float*)d_in[4];
    const float* W2    = (const float*)d_in[5];
    const float* b2    = (const float*)d_in[6];
    const float* scale = (const float*)d_in[7];
    float* out = (float*)d_out;
    float* ws  = (float*)d_ws;

    float* logits = ws + WS_LOGITS;
    float* part   = ws + WS_PART;
    unsigned short* W1h = (unsigned short*)(ws + WS_W1H);
    unsigned short* W1l = (unsigned short*)(ws + WS_W1L);
    unsigned short* W2t = (unsigned short*)(ws + WS_W2T);
    float* b1p  = ws + WS_B1P;
    float* smax = ws + WS_SMAX;
    float* sinv = ws + WS_SINV;

    hipLaunchKernelGGL(prep_k, dim3(256), dim3(256), 0, stream,
                       W1, b1, W2, W1h, W1l, W2t, b1p);
    hipLaunchKernelGGL(scorer_k, dim3(N_TOK / 64), dim3(256), 0, stream,
                       x, gamma, beta, W1h, W1l, W2t, b1p, b2, scale, logits);
    hipLaunchKernelGGL(stats_k, dim3(KTOK), dim3(256), 0, stream,
                       logits, smax, sinv);
    hipLaunchKernelGGL(agg_k, dim3(128, 4), dim3(256), 0, stream,
                       x, logits, smax, sinv, part);
    hipLaunchKernelGGL(reduce_k, dim3(128), dim3(256), 0, stream,
                       part, out);
}

// Round 3
// 169.135 us; speedup vs baseline: 2.8507x; 1.5952x over previous
//
#include <hip/hip_runtime.h>
#include <math.h>

#define N_TOK 65536
#define DIM   512
#define HID   102
#define HPAD  128
#define KTOK  64
#define NBLK  2048          // scorer blocks (32 tokens each)
#define LN_EPS 1e-5f

typedef __attribute__((ext_vector_type(8))) short short8;
typedef __attribute__((ext_vector_type(4))) float f32x4;

// ws layout (float offsets)
#define WS_LOGITS 0u
#define WS_PART   4194304u                 // 128*64*512
#define WS_PM     (WS_PART + 4194304u)     // 2048*64
#define WS_PS     (WS_PM + 131072u)        // 2048*64
#define WS_W1B    (WS_PS + 131072u)        // 65536 ushort
#define WS_W2T    (WS_W1B + 32768u)        // 8192 ushort
#define WS_B1P    (WS_W2T + 4096u)
#define WS_SMAX   (WS_B1P + 128u)
#define WS_SINV   (WS_SMAX + 64u)

__device__ __forceinline__ unsigned short f2bf(float f) {
    unsigned int u = __float_as_uint(f);
    unsigned int r = (u + 0x7fffu + ((u >> 16) & 1u)) >> 16;
    return (unsigned short)r;
}

// ---------------- prep: bf16 weights, transposed/padded ----------------
__global__ __launch_bounds__(256) void prep_k(const float* __restrict__ W1,
                                              const float* __restrict__ b1,
                                              const float* __restrict__ W2,
                                              unsigned short* __restrict__ W1b,
                                              unsigned short* __restrict__ W2t,
                                              float* __restrict__ b1p) {
    const int idx = blockIdx.x * 256 + threadIdx.x;   // 0..65535
    {   // W1b [128 j][512 d] = W1[d][j]
        const int j = idx >> 9, d = idx & 511;
        W1b[idx] = (j < HID) ? f2bf(W1[d * HID + j]) : (unsigned short)0;
    }
    if (idx < KTOK * HPAD) {  // W2t [64 k][128 j] = W2[j][k]
        const int k = idx >> 7, j = idx & 127;
        W2t[idx] = (j < HID) ? f2bf(W2[j * KTOK + k]) : (unsigned short)0;
    }
    if (idx < HPAD) b1p[idx] = (idx < HID) ? b1[idx] : 0.0f;
}

// ------- scorer: LN + fc1(MFMA) + GELU + fc2(MFMA) + partial softmax -------
__global__ __launch_bounds__(256, 4) void scorer_k(const float* __restrict__ x,
                                                   const float* __restrict__ gamma,
                                                   const float* __restrict__ beta,
                                                   const unsigned short* __restrict__ W1b,
                                                   const unsigned short* __restrict__ W2t,
                                                   const float* __restrict__ b1p,
                                                   const float* __restrict__ b2,
                                                   const float* __restrict__ scale,
                                                   float* __restrict__ logits,
                                                   float* __restrict__ pm,
                                                   float* __restrict__ psum) {
    __shared__ char smem[32 * 1024 + 8 * 1024];
    char* xs = smem;                         // [32 rows][1024 B] bf16, XOR-swizzled
    char* hsm = smem + 32 * 1024;            // [32 rows][256 B] bf16, XOR-swizzled
    float* lt = (float*)smem;                // [64 k][32 tok] fp32, aliases xs

    const int tid = threadIdx.x;
    const int lane = tid & 63;
    const int w = tid >> 6;
    const int n0 = blockIdx.x * 32;
    const int l15 = lane & 15;
    const int hi = lane >> 4;

    // ---- LayerNorm: wave w rows w*8..+8, 4-row ILP ----
    {
        const f32x4 g0 = *(const f32x4*)&gamma[lane * 8];
        const f32x4 g1 = *(const f32x4*)&gamma[lane * 8 + 4];
        const f32x4 be0 = *(const f32x4*)&beta[lane * 8];
        const f32x4 be1 = *(const f32x4*)&beta[lane * 8 + 4];
        for (int rr = 0; rr < 2; ++rr) {
            const int row0 = w * 8 + rr * 4;
            f32x4 a[4], b[4];
            float s[4], ss[4];
            #pragma unroll
            for (int r = 0; r < 4; ++r) {
                const float* xr = x + (size_t)(n0 + row0 + r) * DIM;
                a[r] = *(const f32x4*)&xr[lane * 8];
                b[r] = *(const f32x4*)&xr[lane * 8 + 4];
                s[r] = a[r].x + a[r].y + a[r].z + a[r].w +
                       b[r].x + b[r].y + b[r].z + b[r].w;
                ss[r] = a[r].x * a[r].x + a[r].y * a[r].y + a[r].z * a[r].z +
                        a[r].w * a[r].w + b[r].x * b[r].x + b[r].y * b[r].y +
                        b[r].z * b[r].z + b[r].w * b[r].w;
            }
            #pragma unroll
            for (int o = 32; o >= 1; o >>= 1) {
                #pragma unroll
                for (int r = 0; r < 4; ++r) {
                    s[r] += __shfl_xor(s[r], o);
                    ss[r] += __shfl_xor(ss[r], o);
                }
            }
            #pragma unroll
            for (int r = 0; r < 4; ++r) {
                const int row = row0 + r;
                const float mu = s[r] * (1.0f / 512.0f);
                const float inv = rsqrtf(ss[r] * (1.0f / 512.0f) - mu * mu + LN_EPS);
                short8 v;
                v[0] = (short)f2bf((a[r].x - mu) * inv * g0.x + be0.x);
                v[1] = (short)f2bf((a[r].y - mu) * inv * g0.y + be0.y);
                v[2] = (short)f2bf((a[r].z - mu) * inv * g0.z + be0.z);
                v[3] = (short)f2bf((a[r].w - mu) * inv * g0.w + be0.w);
                v[4] = (short)f2bf((b[r].x - mu) * inv * g1.x + be1.x);
                v[5] = (short)f2bf((b[r].y - mu) * inv * g1.y + be1.y);
                v[6] = (short)f2bf((b[r].z - mu) * inv * g1.z + be1.z);
                v[7] = (short)f2bf((b[r].w - mu) * inv * g1.w + be1.w);
                *(short8*)(xs + row * 1024 + ((lane * 16) ^ ((row & 7) << 4))) = v;
            }
        }
    }
    __syncthreads();

    // ---- fc1: wave w -> tokens (w&1)*16..+16, hidden half (w>>1)*64..+64 ----
    {
        const int tg = w & 1, hh = w >> 1;
        const int arow = tg * 16 + l15;
        const char* abase = xs + arow * 1024;
        const int asw = (arow & 7) << 4;
        const unsigned short* wb0 = W1b + (size_t)hh * 4 * 8192 + l15 * 512 + hi * 8;
        f32x4 acc[4] = {};
        #pragma unroll 4
        for (int kc = 0; kc < 16; ++kc) {
            const short8 a = *(const short8*)(abase + ((kc * 64 + hi * 16) ^ asw));
            #pragma unroll
            for (int jj = 0; jj < 4; ++jj) {
                const short8 b = *(const short8*)(wb0 + jj * 8192 + kc * 32);
                acc[jj] = __builtin_amdgcn_mfma_f32_16x16x32_bf16(a, b, acc[jj], 0, 0, 0);
            }
        }
        #pragma unroll
        for (int jj = 0; jj < 4; ++jj) {
            const int col = hh * 64 + jj * 16 + l15;
            const float bias = b1p[col];
            #pragma unroll
            for (int reg = 0; reg < 4; ++reg) {
                const int row = tg * 16 + 4 * hi + reg;
                const float t = acc[jj][reg] + bias;
                const float g = 0.5f * t * (1.0f + erff(t * 0.70710678118f));
                *(unsigned short*)(hsm + row * 256 + ((col * 2) ^ ((row & 7) << 4))) =
                    f2bf(g);
            }
        }
    }
    __syncthreads();

    // ---- fc2: wave w -> tokens (w&1)*16..+16, k half (w>>1)*32..+32 ----
    {
        const int tg = w & 1, kh = w >> 1;
        const int arow = tg * 16 + l15;
        const char* hbase = hsm + arow * 256;
        const int hsw = (arow & 7) << 4;
        f32x4 acc2[2] = {};
        #pragma unroll
        for (int kc = 0; kc < 4; ++kc) {
            const short8 a = *(const short8*)(hbase + ((kc * 64 + hi * 16) ^ hsw));
            #pragma unroll
            for (int nt = 0; nt < 2; ++nt) {
                const int k = (kh * 2 + nt) * 16 + l15;
                const short8 b = *(const short8*)(W2t + k * 128 + kc * 32 + hi * 8);
                acc2[nt] = __builtin_amdgcn_mfma_f32_16x16x32_bf16(a, b, acc2[nt], 0, 0, 0);
            }
        }
        const float sc = scale[0];
        #pragma unroll
        for (int nt = 0; nt < 2; ++nt) {
            const int k = (kh * 2 + nt) * 16 + l15;
            const float bb = b2[k];
            const int ksw = (k & 7) << 4;
            #pragma unroll
            for (int reg = 0; reg < 4; ++reg) {
                const int token = tg * 16 + 4 * hi + reg;
                *(float*)((char*)lt + k * 128 + ((token * 4) ^ ksw)) =
                    (acc2[nt][reg] + bb) * sc;
            }
        }
    }
    __syncthreads();

    // ---- logits store + per-block softmax partials ----
    {
        const int k = tid >> 2, q = tid & 3;
        const int ksw = (k & 7) << 4;
        const char* lrow = (const char*)lt + k * 128;
        const f32x4 v0 = *(const f32x4*)(lrow + ((q * 32) ^ ksw));
        const f32x4 v1 = *(const f32x4*)(lrow + ((q * 32 + 16) ^ ksw));
        float* dst = logits + (size_t)k * N_TOK + n0 + q * 8;
        *(f32x4*)dst = v0;
        *(f32x4*)(dst + 4) = v1;
        float m8 = fmaxf(fmaxf(fmaxf(v0.x, v0.y), fmaxf(v0.z, v0.w)),
                         fmaxf(fmaxf(v1.x, v1.y), fmaxf(v1.z, v1.w)));
        float s8 = __expf(v0.x - m8) + __expf(v0.y - m8) + __expf(v0.z - m8) +
                   __expf(v0.w - m8) + __expf(v1.x - m8) + __expf(v1.y - m8) +
                   __expf(v1.z - m8) + __expf(v1.w - m8);
        #pragma unroll
        for (int o = 1; o <= 2; o <<= 1) {
            const float om = __shfl_xor(m8, o);
            const float os = __shfl_xor(s8, o);
            const float nm = fmaxf(m8, om);
            s8 = s8 * __expf(m8 - nm) + os * __expf(om - nm);
            m8 = nm;
        }
        if (q == 0) {
            pm[blockIdx.x * 64 + k] = m8;
            psum[blockIdx.x * 64 + k] = s8;
        }
    }
}

// ---------------- stats: combine per-block partials ----------------
__global__ __launch_bounds__(256) void stats_k(const float* __restrict__ pm,
                                               const float* __restrict__ psum,
                                               float* __restrict__ smax,
                                               float* __restrict__ sinv) {
    const int k = blockIdx.x;
    const int tid = threadIdx.x;
    __shared__ float rm[4], rs[4];
    float m = -1e30f, s = 0.0f;
    for (int b = tid; b < NBLK; b += 256) {
        const float pmv = pm[b * 64 + k];
        const float psv = psum[b * 64 + k];
        const float nm = fmaxf(m, pmv);
        s = s * __expf(m - nm) + psv * __expf(pmv - nm);
        m = nm;
    }
    #pragma unroll
    for (int o = 32; o >= 1; o >>= 1) {
        const float om = __shfl_xor(m, o);
        const float os = __shfl_xor(s, o);
        const float nm = fmaxf(m, om);
        s = s * __expf(m - nm) + os * __expf(om - nm);
        m = nm;
    }
    if ((tid & 63) == 0) { rm[tid >> 6] = m; rs[tid >> 6] = s; }
    __syncthreads();
    if (tid == 0) {
        float fm = rm[0], fs = rs[0];
        for (int i = 1; i < 4; ++i) {
            const float nm = fmaxf(fm, rm[i]);
            fs = fs * __expf(fm - nm) + rs[i] * __expf(rm[i] - nm);
            fm = nm;
        }
        smax[k] = fm;
        sinv[k] = 1.0f / fs;
    }
}

// ---------------- agg: partial[tb][k][d], 512 tokens/block ----------------
__global__ __launch_bounds__(512, 4) void agg_k(const float* __restrict__ x,
                                                const float* __restrict__ logits,
                                                const float* __restrict__ smax,
                                                const float* __restrict__ sinv,
                                                float* __restrict__ part) {
    __shared__ float ps[64][65];
    const int tid = threadIdx.x;
    const int dg = blockIdx.y;
    const int tb = blockIdx.x;
    const int kq = tid >> 5;            // 0..15 -> k = kq*4..+4
    const int dt = tid & 31;
    const int dbase = dg * 128 + dt * 4;
    const int n_start = tb * 512;
    const int sk = tid >> 3;            // staging: k row 0..63
    const int np = (tid & 7) * 8;       // staging: 8 tokens
    const float mk = smax[sk];
    const float ik = sinv[sk];
    float acc[4][4] = {};

    for (int c = 0; c < 8; ++c) {
        const int n0 = n_start + c * 64;
        const f32x4 va = *(const f32x4*)&logits[(size_t)sk * N_TOK + n0 + np];
        const f32x4 vb = *(const f32x4*)&logits[(size_t)sk * N_TOK + n0 + np + 4];
        __syncthreads();
        ps[sk][np + 0] = __expf(va.x - mk) * ik;
        ps[sk][np + 1] = __expf(va.y - mk) * ik;
        ps[sk][np + 2] = __expf(va.z - mk) * ik;
        ps[sk][np + 3] = __expf(va.w - mk) * ik;
        ps[sk][np + 4] = __expf(vb.x - mk) * ik;
        ps[sk][np + 5] = __expf(vb.y - mk) * ik;
        ps[sk][np + 6] = __expf(vb.z - mk) * ik;
        ps[sk][np + 7] = __expf(vb.w - mk) * ik;
        __syncthreads();
        #pragma unroll 4
        for (int n = 0; n < 64; ++n) {
            const f32x4 xv = *(const f32x4*)&x[(size_t)(n0 + n) * DIM + dbase];
            #pragma unroll
            for (int i = 0; i < 4; ++i) {
                const float p = ps[kq * 4 + i][n];
                acc[i][0] = fmaf(p, xv.x, acc[i][0]);
                acc[i][1] = fmaf(p, xv.y, acc[i][1]);
                acc[i][2] = fmaf(p, xv.z, acc[i][2]);
                acc[i][3] = fmaf(p, xv.w, acc[i][3]);
            }
        }
    }
    #pragma unroll
    for (int i = 0; i < 4; ++i) {
        const int k = kq * 4 + i;
        f32x4 v;
        v.x = acc[i][0]; v.y = acc[i][1]; v.z = acc[i][2]; v.w = acc[i][3];
        *(f32x4*)&part[((size_t)tb * 64 + k) * 512 + dbase] = v;
    }
}

// ---------------- reduce: out[k][d] = sum_tb part[tb][k][d] ----------------
__global__ __launch_bounds__(256) void reduce_k(const float* __restrict__ part,
                                                float* __restrict__ out) {
    const int idx = blockIdx.x * 256 + threadIdx.x;  // 0..32767
    const int k = idx >> 9, d = idx & 511;
    float s = 0.0f;
    for (int tb = 0; tb < 128; ++tb) s += part[((size_t)tb * 64 + k) * 512 + d];
    out[idx] = s;
}

extern "C" void kernel_launch(void* const* d_in, const int* in_sizes, int n_in,
                              void* d_out, int out_size, void* d_ws, size_t ws_size,
                              hipStream_t stream) {
    const float* x     = (const float*)d_in[0];
    const float* gamma = (const float*)d_in[1];
    const float* beta  = (const float*)d_in[2];
    const float* W1    = (const float*)d_in[3];
    const float* b1    = (const float*)d_in[4];
    const float* W2    = (const float*)d_in[5];
    const float* b2    = (const float*)d_in[6];
    const float* scale = (const float*)d_in[7];
    float* out = (float*)d_out;
    float* ws  = (float*)d_ws;

    float* logits = ws + WS_LOGITS;
    float* part   = ws + WS_PART;
    float* pm     = ws + WS_PM;
    float* psum   = ws + WS_PS;
    unsigned short* W1b = (unsigned short*)(ws + WS_W1B);
    unsigned short* W2t = (unsigned short*)(ws + WS_W2T);
    float* b1p  = ws + WS_B1P;
    float* smax = ws + WS_SMAX;
    float* sinv = ws + WS_SINV;

    hipLaunchKernelGGL(prep_k, dim3(256), dim3(256), 0, stream,
                       W1, b1, W2, W1b, W2t, b1p);
    hipLaunchKernelGGL(scorer_k, dim3(NBLK), dim3(256), 0, stream,
                       x, gamma, beta, W1b, W2t, b1p, b2, scale, logits, pm, psum);
    hipLaunchKernelGGL(stats_k, dim3(KTOK), dim3(256), 0, stream,
                       pm, psum, smax, sinv);
    hipLaunchKernelGGL(agg_k, dim3(128, 4), dim3(512), 0, stream,
                       x, logits, smax, sinv, part);
    hipLaunchKernelGGL(reduce_k, dim3(128), dim3(256), 0, stream,
                       part, out);
}